// Round 1
// 406.202 us; speedup vs baseline: 1.0137x; 1.0137x over previous
//
#include <hip/hip_runtime.h>
#include <hip/hip_bf16.h>

#define N 8192
#define IN_F 512
#define OUT_F 64
#define S_SPLIT 16
#define JT (N / S_SPLIT)   // 512 columns per split
#define LDP 536            // LDS row pitch in shorts: 1072 B rows (16B-aligned),
                           // stride = 268 dw ≡ 12 (mod 32) -> <=2-way bank aliasing (free)
#define LOG2E 1.44269504088896340736f

typedef __attribute__((ext_vector_type(8))) short short8;
typedef __attribute__((ext_vector_type(4))) float floatx4;
typedef __attribute__((ext_vector_type(4))) int intx4;

__device__ inline short f2bf(float x) {
    __hip_bfloat16 b = __float2bfloat16(x);
    return __builtin_bit_cast(short, b);
}

__device__ inline float fexp2(float x) {
#if __has_builtin(__builtin_amdgcn_exp2f)
    return __builtin_amdgcn_exp2f(x);
#else
    return exp2f(x);
#endif
}

// K1a: W [512][64] fp32 -> WT [64][512] bf16
__global__ void k_wt(const float* __restrict__ W, short* __restrict__ WT) {
    int idx = blockIdx.x * 256 + threadIdx.x;    // 32768 total
    int k = idx >> 6, f = idx & 63;
    WT[f * IN_F + k] = f2bf(W[k * OUT_F + f]);
}

// K1: WH = h @ W via bf16 MFMA. 512 blocks x 1 wave, 16 rows each.
// Epilogue: WHbT bf16 [64][8192] (LDS transpose) + wh1/wh2 PRE-SCALED by log2e
// (so k_attn can use raw v_exp_f32 = exp2). 1-wave blocks have the full 512-VGPR
// budget -> full K-unroll lets all 32 h-loads pipeline (kernel was latency-bound).
__global__ __launch_bounds__(64) void k_wh(const float* __restrict__ h,
                                           const short* __restrict__ WT,
                                           const float* __restrict__ a,
                                           short* __restrict__ WHbT,
                                           float* __restrict__ wh1,
                                           float* __restrict__ wh2) {
    __shared__ float tile[OUT_F][17];
    int lane = threadIdx.x;
    int n = lane & 15, q = lane >> 4;
    int i0 = blockIdx.x * 16;
    int rowA = i0 + n;
    const float* hp = h + (size_t)rowA * IN_F + q * 8;
    floatx4 acc[4] = {};
#pragma unroll
    for (int k0 = 0; k0 < IN_F; k0 += 32) {
        floatx4 h0 = *(const floatx4*)(hp + k0);
        floatx4 h1 = *(const floatx4*)(hp + k0 + 4);
        short8 af;
#pragma unroll
        for (int j = 0; j < 4; j++) { af[j] = f2bf(h0[j]); af[j + 4] = f2bf(h1[j]); }
#pragma unroll
        for (int b = 0; b < 4; b++) {
            short8 bf_ = *(const short8*)(WT + (b * 16 + n) * IN_F + k0 + q * 8);
            acc[b] = __builtin_amdgcn_mfma_f32_16x16x32_bf16(af, bf_, acc[b], 0, 0, 0);
        }
    }
#pragma unroll
    for (int b = 0; b < 4; b++)
#pragma unroll
        for (int r = 0; r < 4; r++)
            tile[b * 16 + n][q * 4 + r] = acc[b][r];
    float a1v[4], a2v[4];
#pragma unroll
    for (int b = 0; b < 4; b++) { a1v[b] = a[b * 16 + n]; a2v[b] = a[OUT_F + b * 16 + n]; }
#pragma unroll
    for (int r = 0; r < 4; r++) {
        float s1 = 0.f, s2 = 0.f;
#pragma unroll
        for (int b = 0; b < 4; b++) { s1 += acc[b][r] * a1v[b]; s2 += acc[b][r] * a2v[b]; }
#pragma unroll
        for (int m = 1; m <= 8; m <<= 1) {
            s1 += __shfl_xor(s1, m, 64);
            s2 += __shfl_xor(s2, m, 64);
        }
        if (n == 0) {
            wh1[i0 + q * 4 + r] = s1 * LOG2E;
            wh2[i0 + q * 4 + r] = s2 * LOG2E;
        }
    }
    __syncthreads();
    const float* tc = tile[lane];
    short8 s0, s1v;
#pragma unroll
    for (int k = 0; k < 8; k++) { s0[k] = f2bf(tc[k]); s1v[k] = f2bf(tc[k + 8]); }
    *(short8*)(WHbT + (size_t)lane * N + i0) = s0;
    *(short8*)(WHbT + (size_t)lane * N + i0 + 8) = s1v;
}

// K2: fused adjacency-read + mask + leaky_relu + exp2 + (P @ [WH | 1]) partials.
// k_pack is gone: adj int32 is streamed directly here (double-buffered, 2 intx4
// per lane per (rf,s)), overlapping the 256 MB read with the attention VALU/MFMA.
// den comes from a 5th MFMA with a ones-column B fragment (no per-element dsum,
// no shfl reduce). Grid (32,16) x 256 thr; B-tile in LDS (67 KB -> 2 blocks/CU).
__global__ __launch_bounds__(256, 2) void k_attn(const int* __restrict__ adj,
                                                 const short* __restrict__ WHbT,
                                                 const float* __restrict__ wh1,
                                                 const float* __restrict__ wh2,
                                                 float* __restrict__ num_part,
                                                 float* __restrict__ den_part) {
    __shared__ short ldsb[OUT_F * LDP];          // 67 KB
    int tid = threadIdx.x;
    int w = tid >> 6;
    int lane = tid & 63;
    int n = lane & 15, q = lane >> 4;
    int split = blockIdx.y;
    int j0 = split * JT;
    int i0 = blockIdx.x * 256 + w * 64;          // wave's first row

    // stage B-tile: each wave reads one full WHbT row (1KB) per iteration
#pragma unroll
    for (int l = 0; l < 16; l++) {
        int idx = l * 256 + tid;
        int f = idx >> 6, c16 = idx & 63;
        short8 v = *(const short8*)(WHbT + (size_t)f * N + j0 + c16 * 8);
        *(short8*)(ldsb + f * LDP + c16 * 8) = v;
    }
    __syncthreads();

    float wh1f[4];
#pragma unroll
    for (int rf = 0; rf < 4; rf++) wh1f[rf] = wh1[i0 + rf * 16 + n];

    floatx4 acc[4][4] = {};                       // [rf][b]
    floatx4 accd[4] = {};                         // den accumulator (col 0)
    const float* w2p = wh2 + j0 + q * 8;
    const short* lp = ldsb + q * 8;

    // ones B-fragment: B[k][col] = 1 iff col==0 -> D[:,0] = row-sum of A
    short8 onesf = {};
    if (n == 0) {
        short o = f2bf(1.0f);
#pragma unroll
        for (int jj = 0; jj < 8; jj++) onesf[jj] = o;
    }

    const int* ap = adj + j0 + q * 8;
    size_t roff[4];
#pragma unroll
    for (int rf = 0; rf < 4; rf++) roff[rf] = (size_t)(i0 + rf * 16 + n) * N;

    intx4 A0[4], A1[4], B0[4], B1[4];             // adj double-buffer

    auto loads = [&](intx4* D0, intx4* D1, int s) {
#pragma unroll
        for (int rf = 0; rf < 4; rf++) {
            const int* pp = ap + roff[rf] + s * 32;
            D0[rf] = *(const intx4*)pp;
            D1[rf] = *(const intx4*)(pp + 4);
        }
    };

    auto step = [&](const intx4* D0, const intx4* D1, int s) {
        floatx4 w20 = *(const floatx4*)(w2p + s * 32);
        floatx4 w21 = *(const floatx4*)(w2p + s * 32 + 4);
        short8 bfr[4];
#pragma unroll
        for (int b = 0; b < 4; b++)
            bfr[b] = *(const short8*)(lp + (b * 16 + n) * LDP + s * 32);
#pragma unroll
        for (int rf = 0; rf < 4; rf++) {
            float p[8];
#pragma unroll
            for (int jj = 0; jj < 8; jj++) {
                // wh1/wh2 pre-scaled by log2e: exp(leaky(e)) == exp2(max(e*, .01e*))
                float e = wh1f[rf] + ((jj < 4) ? w20[jj] : w21[jj - 4]);
                float el = fmaxf(e, 0.01f * e);
                int av = (jj < 4) ? D0[rf][jj] : D1[rf][jj - 4];
                el = (av > 0) ? el : -1024.0f;    // exp2(-1024) == 0, exact mask
                p[jj] = fexp2(el);
            }
            short8 af;
#pragma unroll
            for (int jj = 0; jj < 8; jj++) af[jj] = f2bf(p[jj]);
#pragma unroll
            for (int b = 0; b < 4; b++)
                acc[rf][b] = __builtin_amdgcn_mfma_f32_16x16x32_bf16(af, bfr[b], acc[rf][b], 0, 0, 0);
            accd[rf] = __builtin_amdgcn_mfma_f32_16x16x32_bf16(af, onesf, accd[rf], 0, 0, 0);
        }
    };

    // software-pipelined: prefetch s+1 while computing s (ping-pong, no
    // runtime-indexed register arrays). (s+2)&15 wrap re-reads split start
    // at the tail -- harmless, keeps loads unconditional.
    loads(A0, A1, 0);
    for (int sp = 0; sp < 8; sp++) {
        int s0 = sp * 2;
        loads(B0, B1, s0 + 1);
        step(A0, A1, s0);
        loads(A0, A1, (s0 + 2) & 15);
        step(B0, B1, s0 + 1);
    }

    // den: C/D layout col = lane&15, row = q*4 + r -> lanes n==0 hold all 16 rows
#pragma unroll
    for (int rf = 0; rf < 4; rf++)
        if (n == 0)
            *(floatx4*)(den_part + (size_t)split * N + i0 + rf * 16 + q * 4) = accd[rf];

    float* np_ = num_part + (size_t)split * N * OUT_F;
#pragma unroll
    for (int rf = 0; rf < 4; rf++)
#pragma unroll
        for (int b = 0; b < 4; b++)
#pragma unroll
            for (int r = 0; r < 4; r++)
                np_[(size_t)(i0 + rf * 16 + q * 4 + r) * OUT_F + b * 16 + n] = acc[rf][b][r];
}

// K3: out = elu( (Σ num_part) / (Σ den_part) )
__global__ void k_final(const float* __restrict__ num_part,
                        const float* __restrict__ den_part,
                        float* __restrict__ out) {
    int idx = blockIdx.x * 256 + threadIdx.x;    // 524288 total
    int row = idx >> 6;
    float s = 0.f, d = 0.f;
#pragma unroll
    for (int sp = 0; sp < S_SPLIT; sp++) {
        s += num_part[(size_t)sp * N * OUT_F + idx];
        d += den_part[sp * N + row];
    }
    float x = s / d;
    out[idx] = (x > 0.f) ? x : (__expf(x) - 1.f);
}

extern "C" void kernel_launch(void* const* d_in, const int* in_sizes, int n_in,
                              void* d_out, int out_size, void* d_ws, size_t ws_size,
                              hipStream_t stream) {
    const float* h = (const float*)d_in[0];
    const int* adj = (const int*)d_in[1];
    const float* W = (const float*)d_in[2];
    const float* a = (const float*)d_in[3];
    float* out = (float*)d_out;

    char* ws = (char*)d_ws;
    short* WHbT     = (short*)(ws);                                  // 1 MB
    short* WT       = (short*)(ws + (size_t)(1 << 20));              // 64 KB
    float* wh1      = (float*)(ws + (size_t)(1 << 20) + (64 << 10)); // 32 KB
    float* wh2      = wh1 + N;                                       // 32 KB
    float* num_p    = (float*)(ws + (size_t)(16 << 20));             // 32 MB
    float* den_p    = (float*)(ws + (size_t)(48 << 20));             // 512 KB

    k_wt<<<dim3(128), dim3(256), 0, stream>>>(W, WT);
    k_wh<<<dim3(N / 16), dim3(64), 0, stream>>>(h, WT, a, WHbT, wh1, wh2);
    k_attn<<<dim3(N / 256, S_SPLIT), dim3(256), 0, stream>>>(adj, WHbT, wh1, wh2,
                                                             num_p, den_p);
    k_final<<<dim3((N * OUT_F) / 256), dim3(256), 0, stream>>>(num_p, den_p, out);
}